// Round 3
// baseline (532.948 us; speedup 1.0000x reference)
//
#include <hip/hip_runtime.h>
#include <hip/hip_bf16.h>

typedef __attribute__((ext_vector_type(8))) short bf16x8;
typedef __attribute__((ext_vector_type(4))) short bf16x4;
typedef __attribute__((ext_vector_type(4))) float f32x4;

#define DEVI static __device__ __forceinline__

constexpr int NAG = 32, DIN = 256, HDIM = 128, ADIM = 32;

// ws layout (bf16 element offsets). Frag order serves both A- and B-orientation:
//   elem ((ks*NM + mt)*64 + lane)*8 + j  <->  W[ks*32 + (lane>>4)*8 + j][mt*16 + (lane&15)]
constexpr int WS_ENC = 0;                  // 256x128
constexpr int WS_H   = 32768;              // 8 mats x 16384
constexpr int WS_QW  = 32768 + 8 * 16384;  // 128x32

// Per-wave private LDS slab: A (8 KB: h -> V -> AO -> h2) + S (2 KB: Qg/Kg/AT).
// 4 waves x 10240 B = 40960 B/block -> 4 blocks/CU (160 KB), 16 INDEPENDENT waves/CU.
constexpr int W_S = 8192, W_SZ = 10240, L_TOT = 4 * W_SZ;

// 16B-chunk XOR swizzles (no pad; pow2 pitches).
// 256B-pitch rows (h/AO/h2, 32x128 bf16):
DEVI int offA(int row, int bcol) {
  return row * 256 + (((bcol >> 4) ^ (row & 15)) << 4) + (bcol & 15);
}
// 64B-pitch rows (V: 128x32, Qg/Kg/AT: 32x32 bf16):
DEVI int offS(int row, int bcol) {
  return row * 64 + (((bcol >> 4) ^ ((row >> 1) & 3)) << 4) + (bcol & 15);
}

DEVI short f2bf(float f) {
  union { float f; unsigned u; } a; a.f = f;
  return (short)((a.u + 0x7fffu + ((a.u >> 16) & 1u)) >> 16);
}

// ---------------- weight prep: coalesced float4 reads, scattered 2B writes ----
__global__ void prep_weights(const float* __restrict__ enc_w,
                             const float* __restrict__ m0, const float* __restrict__ m1,
                             const float* __restrict__ m2, const float* __restrict__ m3,
                             const float* __restrict__ m4, const float* __restrict__ m5,
                             const float* __restrict__ m6, const float* __restrict__ m7,
                             const float* __restrict__ qw,
                             short* __restrict__ ws)
{
  const int blk = blockIdx.x, tid = threadIdx.x;
  const float* src; int base, NM, nsh, f4;
  if (blk < 32) { src = enc_w; base = WS_ENC; NM = 8; nsh = 7; f4 = blk * 256 + tid; }
  else if (blk < 160) {
    const int m = (blk - 32) >> 4;
    if      (m == 0) src = m0; else if (m == 1) src = m1;
    else if (m == 2) src = m2; else if (m == 3) src = m3;
    else if (m == 4) src = m4; else if (m == 5) src = m5;
    else if (m == 6) src = m6; else             src = m7;
    base = WS_H + (m << 14); NM = 8; nsh = 7; f4 = ((blk - 32) & 15) * 256 + tid;
  } else { src = qw; base = WS_QW; NM = 2; nsh = 5; f4 = (blk - 160) * 256 + tid; }
  const int s = f4 * 4;
  const int row = s >> nsh, col0 = s & ((1 << nsh) - 1);
  const float4 v = *(const float4*)(src + s);
  const int j = row & 7, ks = row >> 5, lhi = ((row >> 3) & 3) * 16;
  const float vv[4] = {v.x, v.y, v.z, v.w};
#pragma unroll
  for (int c = 0; c < 4; ++c) {
    const int col = col0 + c;
    const int mt = col >> 4, lane = lhi + (col & 15);
    ws[base + (((ks * NM + mt) * 64 + lane) << 3) + j] = f2bf(vv[c]);
  }
}

// ---------------- one full attention block, single wave, ZERO barriers --------
// In : h in A (offA layout, [agent][feat]);  Out: h2 in A (offA layout)
DEVI void att_block(char* __restrict__ A, char* __restrict__ S,
                    const short* __restrict__ wv, const short* __restrict__ wk,
                    const short* __restrict__ wq, const short* __restrict__ wo,
                    const float* __restrict__ bv, const float* __restrict__ bk,
                    const float* __restrict__ bq, const float* __restrict__ bo,
                    unsigned mb, int lr, int lq, int lane)
{
  const bf16x8* wpv = (const bf16x8*)wv;
  const bf16x8* wpk = (const bf16x8*)wk;
  const bf16x8* wpq = (const bf16x8*)wq;
  const bf16x8* wpo = (const bf16x8*)wo;

  // ---- scores: accumulate over 4 feature-groups g (32 feats each).
  f32x4 sc[2][2];   // [kt][qt]
#pragma unroll
  for (int kt = 0; kt < 2; ++kt)
#pragma unroll
    for (int qt = 0; qt < 2; ++qt) sc[kt][qt] = (f32x4){0.f, 0.f, 0.f, 0.f};

#pragma unroll 1
  for (int g = 0; g < 4; ++g) {
    f32x4 qa[2][2], ka[2][2];   // [f][at]
#pragma unroll
    for (int f = 0; f < 2; ++f)
#pragma unroll
      for (int at = 0; at < 2; ++at) {
        qa[f][at] = (f32x4){0.f, 0.f, 0.f, 0.f};
        ka[f][at] = (f32x4){0.f, 0.f, 0.f, 0.f};
      }
#pragma unroll
    for (int ks = 0; ks < 4; ++ks) {
      bf16x8 hf[2];
#pragma unroll
      for (int at = 0; at < 2; ++at)
        hf[at] = *(const bf16x8*)(A + offA(at * 16 + lr, ks * 64 + lq * 16));
#pragma unroll
      for (int f = 0; f < 2; ++f) {
        const bf16x8 wqf = wpq[(ks * 8 + g * 2 + f) * 64 + lane];
        const bf16x8 wkf = wpk[(ks * 8 + g * 2 + f) * 64 + lane];
#pragma unroll
        for (int at = 0; at < 2; ++at) {
          qa[f][at] = __builtin_amdgcn_mfma_f32_16x16x32_bf16(wqf, hf[at], qa[f][at], 0, 0, 0);
          ka[f][at] = __builtin_amdgcn_mfma_f32_16x16x32_bf16(wkf, hf[at], ka[f][at], 0, 0, 0);
        }
      }
    }
    // stage Qg -> S, read q-frags (intra-wave: DS in-order, no barrier)
#pragma unroll
    for (int f = 0; f < 2; ++f) {
      const float4 b4 = *(const float4*)(bq + (g * 2 + f) * 16 + lq * 4);
      const float bb[4] = {b4.x, b4.y, b4.z, b4.w};
#pragma unroll
      for (int at = 0; at < 2; ++at) {
        bf16x4 s;
#pragma unroll
        for (int r = 0; r < 4; ++r) s[r] = f2bf(fmaxf(qa[f][at][r] + bb[r], 0.f));
        *(bf16x4*)(S + offS(at * 16 + lr, f * 32 + lq * 8)) = s;
      }
    }
    bf16x8 qf[2];
#pragma unroll
    for (int qt = 0; qt < 2; ++qt)
      qf[qt] = *(const bf16x8*)(S + offS(qt * 16 + lr, lq * 16));
    // stage Kg over the same slab, read k-frags
#pragma unroll
    for (int f = 0; f < 2; ++f) {
      const float4 b4 = *(const float4*)(bk + (g * 2 + f) * 16 + lq * 4);
      const float bb[4] = {b4.x, b4.y, b4.z, b4.w};
#pragma unroll
      for (int at = 0; at < 2; ++at) {
        bf16x4 s;
#pragma unroll
        for (int r = 0; r < 4; ++r) s[r] = f2bf(fmaxf(ka[f][at][r] + bb[r], 0.f));
        *(bf16x4*)(S + offS(at * 16 + lr, f * 32 + lq * 8)) = s;
      }
    }
    bf16x8 kf[2];
#pragma unroll
    for (int kt = 0; kt < 2; ++kt)
      kf[kt] = *(const bf16x8*)(S + offS(kt * 16 + lr, lq * 16));
#pragma unroll
    for (int kt = 0; kt < 2; ++kt)
#pragma unroll
      for (int qt = 0; qt < 2; ++qt)
        sc[kt][qt] = __builtin_amdgcn_mfma_f32_16x16x32_bf16(kf[kt], qf[qt], sc[kt][qt], 0, 0, 0);
  }

  // ---- softmax (in-register; lane holds S[k=kt*16+lq*4+r][q=qt*16+lr])
  float ex[2][2][4], rT[2];
#pragma unroll
  for (int qt = 0; qt < 2; ++qt) {
    float l[2][4];
    float M = -3.0e38f;
#pragma unroll
    for (int kt = 0; kt < 2; ++kt)
#pragma unroll
      for (int r = 0; r < 4; ++r) {
        const float v = ((mb >> ((qt * 2 + kt) * 4 + r)) & 1u) ? sc[kt][qt][r] : -9.0e15f;
        l[kt][r] = v;
        M = fmaxf(M, v);
      }
    M = fmaxf(M, __shfl_xor(M, 16));
    M = fmaxf(M, __shfl_xor(M, 32));
    float T = 0.f;
#pragma unroll
    for (int kt = 0; kt < 2; ++kt)
#pragma unroll
      for (int r = 0; r < 4; ++r) { ex[qt][kt][r] = __expf(l[kt][r] - M); T += ex[qt][kt][r]; }
    T += __shfl_xor(T, 16);
    T += __shfl_xor(T, 32);
    rT[qt] = __frcp_rn(T);
  }
  // stage AT -> S  ([q][k], 64B rows)
#pragma unroll
  for (int qt = 0; qt < 2; ++qt)
#pragma unroll
    for (int kt = 0; kt < 2; ++kt) {
      bf16x4 s;
#pragma unroll
      for (int r = 0; r < 4; ++r) s[r] = f2bf(ex[qt][kt][r] * rT[qt]);
      *(bf16x4*)(S + offS(qt * 16 + lr, kt * 32 + lq * 8)) = s;
    }

  // ---- V = relu(h Wv + bv): preload h frags (h dead after), chunked acc ------
  {
    bf16x8 hfr[2][4];
#pragma unroll
    for (int b = 0; b < 2; ++b)
#pragma unroll
      for (int ks = 0; ks < 4; ++ks)
        hfr[b][ks] = *(const bf16x8*)(A + offA(b * 16 + lr, ks * 64 + lq * 16));
    // h fully in regs; safe to overwrite A with vT[feat][agent] chunk by chunk
#pragma unroll 1
    for (int fc = 0; fc < 4; ++fc) {
      f32x4 va[2][2];   // [agent-tile][fi]
#pragma unroll
      for (int b = 0; b < 2; ++b)
#pragma unroll
        for (int fi = 0; fi < 2; ++fi) va[b][fi] = (f32x4){0.f, 0.f, 0.f, 0.f};
#pragma unroll
      for (int ks = 0; ks < 4; ++ks)
#pragma unroll
        for (int fi = 0; fi < 2; ++fi) {
          const bf16x8 wvf = wpv[(ks * 8 + fc * 2 + fi) * 64 + lane];
#pragma unroll
          for (int b = 0; b < 2; ++b)
            va[b][fi] = __builtin_amdgcn_mfma_f32_16x16x32_bf16(hfr[b][ks], wvf, va[b][fi], 0, 0, 0);
        }
#pragma unroll
      for (int fi = 0; fi < 2; ++fi) {
        const int f = fc * 2 + fi;
        const float bvv = bv[f * 16 + lr];
#pragma unroll
        for (int b = 0; b < 2; ++b) {
          bf16x4 s;
#pragma unroll
          for (int r = 0; r < 4; ++r) s[r] = f2bf(fmaxf(va[b][fi][r] + bvv, 0.f));
          *(bf16x4*)(A + offS(f * 16 + lr, b * 32 + lq * 8)) = s;
        }
      }
    }
  }

  // ---- PV: AO[q][feat] accumulated in regs (A holds V), then written to A ----
  {
    bf16x8 atf[2];
#pragma unroll
    for (int qt = 0; qt < 2; ++qt)
      atf[qt] = *(const bf16x8*)(S + offS(qt * 16 + lr, lq * 16));
    bf16x4 ao[2][8];
#pragma unroll
    for (int f = 0; f < 8; ++f) {
      const bf16x8 vf = *(const bf16x8*)(A + offS(f * 16 + lr, lq * 16));
#pragma unroll
      for (int qt = 0; qt < 2; ++qt) {
        const f32x4 p = __builtin_amdgcn_mfma_f32_16x16x32_bf16(
            vf, atf[qt], (f32x4){0.f, 0.f, 0.f, 0.f}, 0, 0, 0);
#pragma unroll
        for (int r = 0; r < 4; ++r) ao[qt][f][r] = f2bf(p[r]);
      }
    }
    // all V reads done; overwrite A with AO (offA layout)
#pragma unroll
    for (int qt = 0; qt < 2; ++qt)
#pragma unroll
      for (int f = 0; f < 8; ++f)
        *(bf16x4*)(A + offA(qt * 16 + lr, f * 32 + lq * 8)) = ao[qt][f];
  }

  // ---- outproj: h2 = relu(AO Wo + bo), sequential per agent-tile -------------
  // at=0 writes rows 0-15 (bytes 0-4095); at=1 reads rows 16-31 -> disjoint, safe.
#pragma unroll 1
  for (int at = 0; at < 2; ++at) {
    bf16x8 aof[4];
#pragma unroll
    for (int ks = 0; ks < 4; ++ks)
      aof[ks] = *(const bf16x8*)(A + offA(at * 16 + lr, ks * 64 + lq * 16));
    f32x4 ha[8];
#pragma unroll
    for (int f = 0; f < 8; ++f) ha[f] = (f32x4){0.f, 0.f, 0.f, 0.f};
#pragma unroll
    for (int ks = 0; ks < 4; ++ks)
#pragma unroll
      for (int f = 0; f < 8; ++f)
        ha[f] = __builtin_amdgcn_mfma_f32_16x16x32_bf16(wpo[(ks * 8 + f) * 64 + lane], aof[ks], ha[f], 0, 0, 0);
#pragma unroll
    for (int f = 0; f < 8; ++f) {
      const float4 b4 = *(const float4*)(bo + f * 16 + lq * 4);
      const float bb[4] = {b4.x, b4.y, b4.z, b4.w};
      bf16x4 s;
#pragma unroll
      for (int r = 0; r < 4; ++r) s[r] = f2bf(fmaxf(ha[f][r] + bb[r], 0.f));
      *(bf16x4*)(A + offA(at * 16 + lr, f * 32 + lq * 8)) = s;
    }
  }
}

// ---------------- fused forward: one WAVE = 1 batch element; no __syncthreads --
__global__ __launch_bounds__(256, 4)
void dgn_main(const float* __restrict__ x, const float* __restrict__ mask,
              const float* __restrict__ enc_b,
              const float* __restrict__ b1v, const float* __restrict__ b1k,
              const float* __restrict__ b1q, const float* __restrict__ b1o,
              const float* __restrict__ b2v, const float* __restrict__ b2k,
              const float* __restrict__ b2q, const float* __restrict__ b2o,
              const float* __restrict__ qb,
              const short* __restrict__ wf,
              float* __restrict__ out)
{
  __shared__ __align__(16) char smem[L_TOT];
  const int tid = threadIdx.x;
  const int wv4 = tid >> 6, lane = tid & 63;
  const int lr = lane & 15, lq = lane >> 4;
  const int b0 = blockIdx.x * 4 + wv4;
  char* A = smem + wv4 * W_SZ;
  char* S = A + W_S;

  // pack mask into 16 bits/lane: bit (qt*2+kt)*4+r <-> mask[b0][qt*16+lr][kt*16+lq*4+r]
  unsigned mb = 0;
  {
    const float* mp = mask + (size_t)b0 * (NAG * NAG);
#pragma unroll
    for (int qt = 0; qt < 2; ++qt)
#pragma unroll
      for (int kt = 0; kt < 2; ++kt) {
        const float4 m4 = *(const float4*)(mp + (qt * 16 + lr) * 32 + kt * 16 + lq * 4);
        const float mm[4] = {m4.x, m4.y, m4.z, m4.w};
#pragma unroll
        for (int r = 0; r < 4; ++r)
          if (mm[r] != 0.f) mb |= 1u << ((qt * 2 + kt) * 4 + r);
      }
  }

  // ---- encoder: h1 = relu(x W_enc + b) -> A (offA, [agent][feat]), sequential
  {
    const bf16x8* wpe = (const bf16x8*)(wf + WS_ENC);
#pragma unroll 1
    for (int at = 0; at < 2; ++at) {
      f32x4 acc[8];
#pragma unroll
      for (int f = 0; f < 8; ++f) acc[f] = (f32x4){0.f, 0.f, 0.f, 0.f};
      const float* xr = x + ((size_t)b0 * NAG + at * 16 + lr) * DIN + lq * 8;
#pragma unroll
      for (int ks = 0; ks < 8; ++ks) {
        const float4 xa = *(const float4*)(xr + ks * 32);
        const float4 xb = *(const float4*)(xr + ks * 32 + 4);
        bf16x8 xf;
        xf[0] = f2bf(xa.x); xf[1] = f2bf(xa.y); xf[2] = f2bf(xa.z); xf[3] = f2bf(xa.w);
        xf[4] = f2bf(xb.x); xf[5] = f2bf(xb.y); xf[6] = f2bf(xb.z); xf[7] = f2bf(xb.w);
#pragma unroll
        for (int f = 0; f < 8; ++f)
          acc[f] = __builtin_amdgcn_mfma_f32_16x16x32_bf16(wpe[(ks * 8 + f) * 64 + lane], xf, acc[f], 0, 0, 0);
      }
#pragma unroll
      for (int f = 0; f < 8; ++f) {
        const float4 b4 = *(const float4*)(enc_b + f * 16 + lq * 4);
        const float bb[4] = {b4.x, b4.y, b4.z, b4.w};
        bf16x4 s;
#pragma unroll
        for (int r = 0; r < 4; ++r) s[r] = f2bf(fmaxf(acc[f][r] + bb[r], 0.f));
        *(bf16x4*)(A + offA(at * 16 + lr, f * 32 + lq * 8)) = s;
      }
    }
  }

  att_block(A, S,
            wf + WS_H + 0 * 16384, wf + WS_H + 1 * 16384,
            wf + WS_H + 2 * 16384, wf + WS_H + 3 * 16384,
            b1v, b1k, b1q, b1o, mb, lr, lq, lane);

  att_block(A, S,
            wf + WS_H + 4 * 16384, wf + WS_H + 5 * 16384,
            wf + WS_H + 6 * 16384, wf + WS_H + 7 * 16384,
            b2v, b2k, b2q, b2o, mb, lr, lq, lane);

  // ---- head: q = h3 qw + qb  (h3 in A)
  {
    bf16x8 hf2[2][4];
#pragma unroll
    for (int ag = 0; ag < 2; ++ag)
#pragma unroll
      for (int ks = 0; ks < 4; ++ks)
        hf2[ag][ks] = *(const bf16x8*)(A + offA(ag * 16 + lr, ks * 64 + lq * 16));
    f32x4 ho[2][2];   // [act-tile][agent-tile]
#pragma unroll
    for (int a = 0; a < 2; ++a)
#pragma unroll
      for (int ag = 0; ag < 2; ++ag) ho[a][ag] = (f32x4){0.f, 0.f, 0.f, 0.f};
    const bf16x8* wpq2 = (const bf16x8*)(wf + WS_QW);
#pragma unroll
    for (int ks = 0; ks < 4; ++ks)
#pragma unroll
      for (int a = 0; a < 2; ++a) {
        const bf16x8 wfr = wpq2[(ks * 2 + a) * 64 + lane];
#pragma unroll
        for (int ag = 0; ag < 2; ++ag)
          ho[a][ag] = __builtin_amdgcn_mfma_f32_16x16x32_bf16(wfr, hf2[ag][ks], ho[a][ag], 0, 0, 0);
      }
#pragma unroll
    for (int a = 0; a < 2; ++a) {
      const float4 b4 = *(const float4*)(qb + a * 16 + lq * 4);
#pragma unroll
      for (int ag = 0; ag < 2; ++ag) {
        float* op = out + ((size_t)b0 * NAG + ag * 16 + lr) * ADIM + a * 16 + lq * 4;
        float4 o;
        o.x = ho[a][ag][0] + b4.x; o.y = ho[a][ag][1] + b4.y;
        o.z = ho[a][ag][2] + b4.z; o.w = ho[a][ag][3] + b4.w;
        *(float4*)op = o;
      }
    }
  }
}

extern "C" void kernel_launch(void* const* d_in, const int* in_sizes, int n_in,
                              void* d_out, int out_size, void* d_ws, size_t ws_size,
                              hipStream_t stream)
{
  const float* x     = (const float*)d_in[0];
  const float* mask  = (const float*)d_in[1];
  const float* enc_w = (const float*)d_in[2];
  const float* enc_b = (const float*)d_in[3];
  const float* a1_vw = (const float*)d_in[4];
  const float* a1_vb = (const float*)d_in[5];
  const float* a1_kw = (const float*)d_in[6];
  const float* a1_kb = (const float*)d_in[7];
  const float* a1_qw = (const float*)d_in[8];
  const float* a1_qb = (const float*)d_in[9];
  const float* a1_ow = (const float*)d_in[10];
  const float* a1_ob = (const float*)d_in[11];
  const float* a2_vw = (const float*)d_in[12];
  const float* a2_vb = (const float*)d_in[13];
  const float* a2_kw = (const float*)d_in[14];
  const float* a2_kb = (const float*)d_in[15];
  const float* a2_qw = (const float*)d_in[16];
  const float* a2_qb = (const float*)d_in[17];
  const float* a2_ow = (const float*)d_in[18];
  const float* a2_ob = (const float*)d_in[19];
  const float* q_w   = (const float*)d_in[20];
  const float* q_b   = (const float*)d_in[21];
  short* ws = (short*)d_ws;

  prep_weights<<<164, 256, 0, stream>>>(
      enc_w, a1_vw, a1_kw, a1_qw, a1_ow, a2_vw, a2_kw, a2_qw, a2_ow, q_w, ws);

  dgn_main<<<1024, 256, 0, stream>>>(
      x, mask, enc_b,
      a1_vb, a1_kb, a1_qb, a1_ob,
      a2_vb, a2_kb, a2_qb, a2_ob,
      q_b, ws, (float*)d_out);
}

// Round 4
// 300.626 us; speedup vs baseline: 1.7728x; 1.7728x over previous
//
#include <hip/hip_runtime.h>
#include <hip/hip_bf16.h>

typedef __attribute__((ext_vector_type(8))) short bf16x8;
typedef __attribute__((ext_vector_type(4))) short bf16x4;
typedef __attribute__((ext_vector_type(4))) float f32x4;

#define DEVI static __device__ __forceinline__

constexpr int NAG = 32, DIN = 256, HDIM = 128, ADIM = 32;

// ws layout (bf16 element offsets). Frag order serves both A- and B-orientation:
//   elem ((ks*NM + mt)*64 + lane)*8 + j  <->  W[ks*32 + (lane>>4)*8 + j][mt*16 + (lane&15)]
constexpr int WS_ENC = 0;                  // 256x128
constexpr int WS_H   = 32768;              // 8 mats x 16384
constexpr int WS_QW  = 32768 + 8 * 16384;  // 128x32

// LDS: four 8 KiB swizzled buffers = 32768 B. VGPR cap 128 -> 4 blocks/CU.
constexpr int L_P0 = 0, L_P1 = 8192, L_P2 = 16384, L_PV = 24576, L_TOT = 32768;

// 16B-chunk XOR swizzle; ROWB = row pitch in bytes (pow2).
// b128 frag reads (rows vary per lane, chunk fixed): chunk^=row&15 -> any 8
// consecutive lanes hit 8 distinct 16B slots. 8B epilogue stores: 2-way (free).
template<int ROWB>
DEVI int offR(int row, int bcol) {
  return row * ROWB + (((bcol >> 4) ^ (row & 15)) << 4) + (bcol & 15);
}
// 64B-row buffers (V: [128][32] bf16, AT: [32][32] bf16): chunk ^= (row>>1)&3.
DEVI int offVA(int row, int bcol) {
  return row * 64 + (((bcol >> 4) ^ ((row >> 1) & 3)) << 4) + (bcol & 15);
}

DEVI short f2bf(float f) {
  union { float f; unsigned u; } a; a.f = f;
  return (short)((a.u + 0x7fffu + ((a.u >> 16) & 1u)) >> 16);
}

// Soft barrier: LDS-producer/consumer sync WITHOUT the vmcnt(0) drain that
// __syncthreads() emits. All inter-wave deps in this kernel are LDS-carried.
DEVI void sbar() {
  asm volatile("s_waitcnt lgkmcnt(0)\n\ts_barrier" ::: "memory");
}

// ---------------- weight prep: coalesced float4 reads, scattered 2B writes ----
__global__ void prep_weights(const float* __restrict__ enc_w,
                             const float* __restrict__ m0, const float* __restrict__ m1,
                             const float* __restrict__ m2, const float* __restrict__ m3,
                             const float* __restrict__ m4, const float* __restrict__ m5,
                             const float* __restrict__ m6, const float* __restrict__ m7,
                             const float* __restrict__ qw,
                             short* __restrict__ ws)
{
  const int blk = blockIdx.x, tid = threadIdx.x;
  const float* src; int base, NM, nsh, f4;
  if (blk < 32) { src = enc_w; base = WS_ENC; NM = 8; nsh = 7; f4 = blk * 256 + tid; }
  else if (blk < 160) {
    const int m = (blk - 32) >> 4;
    if      (m == 0) src = m0; else if (m == 1) src = m1;
    else if (m == 2) src = m2; else if (m == 3) src = m3;
    else if (m == 4) src = m4; else if (m == 5) src = m5;
    else if (m == 6) src = m6; else             src = m7;
    base = WS_H + (m << 14); NM = 8; nsh = 7; f4 = ((blk - 32) & 15) * 256 + tid;
  } else { src = qw; base = WS_QW; NM = 2; nsh = 5; f4 = (blk - 160) * 256 + tid; }
  const int s = f4 * 4;
  const int row = s >> nsh, col0 = s & ((1 << nsh) - 1);
  const float4 v = *(const float4*)(src + s);
  const int j = row & 7, ks = row >> 5, lhi = ((row >> 3) & 3) * 16;
  const float vv[4] = {v.x, v.y, v.z, v.w};
#pragma unroll
  for (int c = 0; c < 4; ++c) {
    const int col = col0 + c;
    const int mt = col >> 4, lane = lhi + (col & 15);
    ws[base + (((ks * NM + mt) * 64 + lane) << 3) + j] = f2bf(vv[c]);
  }
}

// ---------------- swapped linear on 4 waves: dst[agent][feat], wave = feat group -
template<int KSTEPS, bool RELU, int SRB>
DEVI void linearSw4(const char* __restrict__ src,
                    const short* __restrict__ wfrag, const float* __restrict__ bias,
                    char* __restrict__ dst,
                    int mg, int lr, int lq, int lane)
{
  f32x4 acc[2][2];
#pragma unroll
  for (int a = 0; a < 2; ++a)
#pragma unroll
    for (int b = 0; b < 2; ++b) acc[a][b] = (f32x4){0.f, 0.f, 0.f, 0.f};

  const bf16x8* wp = (const bf16x8*)wfrag;
  __builtin_amdgcn_s_setprio(1);
#pragma unroll
  for (int ks = 0; ks < KSTEPS; ++ks) {
    bf16x8 hb[2];
#pragma unroll
    for (int b = 0; b < 2; ++b)
      hb[b] = *(const bf16x8*)(src + offR<SRB>(b * 16 + lr, ks * 64 + lq * 16));
#pragma unroll
    for (int a = 0; a < 2; ++a) {
      const bf16x8 wa = wp[(ks * 8 + mg * 2 + a) * 64 + lane];
#pragma unroll
      for (int b = 0; b < 2; ++b)
        acc[a][b] = __builtin_amdgcn_mfma_f32_16x16x32_bf16(wa, hb[b], acc[a][b], 0, 0, 0);
    }
  }
  __builtin_amdgcn_s_setprio(0);
#pragma unroll
  for (int a = 0; a < 2; ++a) {
    const float4 bv = *(const float4*)(bias + (mg * 2 + a) * 16 + lq * 4);
    const float bb[4] = {bv.x, bv.y, bv.z, bv.w};
#pragma unroll
    for (int b = 0; b < 2; ++b) {
      bf16x4 s;
#pragma unroll
      for (int r = 0; r < 4; ++r) {
        float v = acc[a][b][r] + bb[r];
        if (RELU) v = fmaxf(v, 0.f);
        s[r] = f2bf(v);
      }
      *(bf16x4*)(dst + offR<256>(b * 16 + lr, (mg * 2 + a) * 32 + lq * 8)) = s;
    }
  }
}

// ---------------- fused QKV: one h-read pass feeds q,k (swapped) and v (normal) -
DEVI void qkv_pass4(const char* __restrict__ h,
                    const short* __restrict__ wq, const short* __restrict__ wk,
                    const short* __restrict__ wv,
                    const float* __restrict__ bq, const float* __restrict__ bk,
                    const float* __restrict__ bv,
                    char* __restrict__ Q, char* __restrict__ K, char* __restrict__ V,
                    int mg, int lr, int lq, int lane)
{
  f32x4 qa[2][2], ka[2][2], va[2][2];
#pragma unroll
  for (int a = 0; a < 2; ++a)
#pragma unroll
    for (int b = 0; b < 2; ++b) {
      qa[a][b] = (f32x4){0.f, 0.f, 0.f, 0.f};
      ka[a][b] = (f32x4){0.f, 0.f, 0.f, 0.f};
      va[a][b] = (f32x4){0.f, 0.f, 0.f, 0.f};
    }
  const bf16x8* wpq = (const bf16x8*)wq;
  const bf16x8* wpk = (const bf16x8*)wk;
  const bf16x8* wpv = (const bf16x8*)wv;
  __builtin_amdgcn_s_setprio(1);
#pragma unroll
  for (int ks = 0; ks < 4; ++ks) {
    bf16x8 hf[2];
#pragma unroll
    for (int b = 0; b < 2; ++b)
      hf[b] = *(const bf16x8*)(h + offR<256>(b * 16 + lr, ks * 64 + lq * 16));
#pragma unroll
    for (int a = 0; a < 2; ++a) {
      const bf16x8 wqf = wpq[(ks * 8 + mg * 2 + a) * 64 + lane];
      const bf16x8 wkf = wpk[(ks * 8 + mg * 2 + a) * 64 + lane];
      const bf16x8 wvf = wpv[(ks * 8 + mg * 2 + a) * 64 + lane];
#pragma unroll
      for (int b = 0; b < 2; ++b) {
        qa[a][b] = __builtin_amdgcn_mfma_f32_16x16x32_bf16(wqf, hf[b], qa[a][b], 0, 0, 0);
        ka[a][b] = __builtin_amdgcn_mfma_f32_16x16x32_bf16(wkf, hf[b], ka[a][b], 0, 0, 0);
        va[b][a] = __builtin_amdgcn_mfma_f32_16x16x32_bf16(hf[b], wvf, va[b][a], 0, 0, 0);
      }
    }
  }
  __builtin_amdgcn_s_setprio(0);
  // q, k epilogues: lane holds 4 consecutive features for fixed agent
#pragma unroll
  for (int a = 0; a < 2; ++a) {
    const float4 bq4 = *(const float4*)(bq + (mg * 2 + a) * 16 + lq * 4);
    const float4 bk4 = *(const float4*)(bk + (mg * 2 + a) * 16 + lq * 4);
    const float qb4[4] = {bq4.x, bq4.y, bq4.z, bq4.w};
    const float kb4[4] = {bk4.x, bk4.y, bk4.z, bk4.w};
#pragma unroll
    for (int b = 0; b < 2; ++b) {
      bf16x4 sq, sk;
#pragma unroll
      for (int r = 0; r < 4; ++r) {
        sq[r] = f2bf(fmaxf(qa[a][b][r] + qb4[r], 0.f));
        sk[r] = f2bf(fmaxf(ka[a][b][r] + kb4[r], 0.f));
      }
      const int off = offR<256>(b * 16 + lr, (mg * 2 + a) * 32 + lq * 8);
      *(bf16x4*)(Q + off) = sq;
      *(bf16x4*)(K + off) = sk;
    }
  }
  // v epilogue: normal orientation -> vT[feat][agent], 4 consecutive agents/lane
#pragma unroll
  for (int a = 0; a < 2; ++a) {
    const float bvv = bv[(mg * 2 + a) * 16 + lr];
#pragma unroll
    for (int b = 0; b < 2; ++b) {
      bf16x4 sv;
#pragma unroll
      for (int r = 0; r < 4; ++r)
        sv[r] = f2bf(fmaxf(va[b][a][r] + bvv, 0.f));
      *(bf16x4*)(V + offVA((mg * 2 + a) * 16 + lr, b * 32 + lq * 8)) = sv;
    }
  }
}

// ---------------- scores + softmax on waves 0,1 (qt = wave), in-register -------
// mask bits preloaded once per kernel (bit kt*4+r for this wave's qt).
DEVI void scores_pass4(const char* __restrict__ Q, const char* __restrict__ K,
                       char* __restrict__ AT,
                       unsigned mb, int qt, int lr, int lq)
{
  f32x4 sc[2];
  sc[0] = (f32x4){0.f, 0.f, 0.f, 0.f};
  sc[1] = (f32x4){0.f, 0.f, 0.f, 0.f};
  __builtin_amdgcn_s_setprio(1);
#pragma unroll
  for (int ks = 0; ks < 4; ++ks) {
    const bf16x8 qf = *(const bf16x8*)(Q + offR<256>(qt * 16 + lr, ks * 64 + lq * 16));
#pragma unroll
    for (int kt = 0; kt < 2; ++kt) {
      const bf16x8 kf = *(const bf16x8*)(K + offR<256>(kt * 16 + lr, ks * 64 + lq * 16));
      sc[kt] = __builtin_amdgcn_mfma_f32_16x16x32_bf16(kf, qf, sc[kt], 0, 0, 0);
    }
  }
  __builtin_amdgcn_s_setprio(0);
  // lane: q = qt*16+lr (fixed), k = kt*16 + lq*4 + r  (8 logits)
  float l[2][4];
  float M = -3.0e38f;
#pragma unroll
  for (int kt = 0; kt < 2; ++kt)
#pragma unroll
    for (int r = 0; r < 4; ++r) {
      // mask is exactly 0.0/1.0 -> select == scores*mask - 9e15*(1-mask)
      const float v = ((mb >> (kt * 4 + r)) & 1u) ? sc[kt][r] : -9.0e15f;
      l[kt][r] = v;
      M = fmaxf(M, v);
    }
  M = fmaxf(M, __shfl_xor(M, 16));
  M = fmaxf(M, __shfl_xor(M, 32));
  float e[2][4], T = 0.f;
#pragma unroll
  for (int kt = 0; kt < 2; ++kt)
#pragma unroll
    for (int r = 0; r < 4; ++r) { e[kt][r] = __expf(l[kt][r] - M); T += e[kt][r]; }
  T += __shfl_xor(T, 16);
  T += __shfl_xor(T, 32);
  const float rT = __frcp_rn(T);
#pragma unroll
  for (int kt = 0; kt < 2; ++kt) {
    bf16x4 s;
#pragma unroll
    for (int r = 0; r < 4; ++r) s[r] = f2bf(e[kt][r] * rT);
    *(bf16x4*)(AT + offVA(qt * 16 + lr, kt * 32 + lq * 8)) = s;
  }
}

// ---------------- PV: attout[q][feat] = att @ v  (A=vT, B=AT) -------------------
DEVI void pv_pass4(const char* __restrict__ V, const char* __restrict__ AT,
                   char* __restrict__ AO, int wave, int lr, int lq)
{
  bf16x8 atf[2];
#pragma unroll
  for (int qt = 0; qt < 2; ++qt)
    atf[qt] = *(const bf16x8*)(AT + offVA(qt * 16 + lr, lq * 16));
  __builtin_amdgcn_s_setprio(1);
#pragma unroll
  for (int fi = 0; fi < 2; ++fi) {
    const int f2 = wave * 2 + fi;
    const bf16x8 vf = *(const bf16x8*)(V + offVA(f2 * 16 + lr, lq * 16));
#pragma unroll
    for (int qt = 0; qt < 2; ++qt) {
      const f32x4 p = __builtin_amdgcn_mfma_f32_16x16x32_bf16(
          vf, atf[qt], (f32x4){0.f, 0.f, 0.f, 0.f}, 0, 0, 0);
      bf16x4 s;
#pragma unroll
      for (int r = 0; r < 4; ++r) s[r] = f2bf(p[r]);
      *(bf16x4*)(AO + offR<256>(qt * 16 + lr, f2 * 32 + lq * 8)) = s;
    }
  }
  __builtin_amdgcn_s_setprio(0);
}

DEVI void att_block4(const char* Rh, char* RQ, char* RK, char* RV,
                     char* RAT, char* RAO, char* Rout,
                     const short* wv, const short* wk, const short* wq, const short* wo,
                     const float* bv, const float* bk, const float* bq, const float* bo,
                     unsigned mb, int wave, int lr, int lq, int lane)
{
  qkv_pass4(Rh, wq, wk, wv, bq, bk, bv, RQ, RK, RV, wave, lr, lq, lane);
  sbar();
  if (wave < 2) scores_pass4(RQ, RK, RAT, mb, wave, lr, lq);
  sbar();
  pv_pass4(RV, RAT, RAO, wave, lr, lq);
  sbar();
  linearSw4<4, true, 256>(RAO, wo, bo, Rout, wave, lr, lq, lane);
  sbar();
}

// ---------------- fused forward: one block (256 thr) = 1 batch element ---------
__global__ __launch_bounds__(256, 4)
void dgn_main(const float* __restrict__ x, const float* __restrict__ mask,
              const float* __restrict__ enc_b,
              const float* __restrict__ b1v, const float* __restrict__ b1k,
              const float* __restrict__ b1q, const float* __restrict__ b1o,
              const float* __restrict__ b2v, const float* __restrict__ b2k,
              const float* __restrict__ b2q, const float* __restrict__ b2o,
              const float* __restrict__ qb,
              const short* __restrict__ wf,
              float* __restrict__ out)
{
  __shared__ __align__(16) char smem[L_TOT];
  char* P0 = smem + L_P0;
  char* P1 = smem + L_P1;
  char* P2 = smem + L_P2;
  char* PV = smem + L_PV;
  char* XB = smem + L_P1;   // x staging [32][256] bf16 swizzled = 16384 B over P1+P2

  const int tid = threadIdx.x;
  const int wave = tid >> 6, lane = tid & 63;
  const int lr = lane & 15, lq = lane >> 4;
  const int b0 = blockIdx.x;

  // mask bit-pack (waves 0,1 only; this wave's q-tile = wave):
  // bit kt*4+r <-> mask[b0][wave*16+lr][kt*16+lq*4+r]. Reused by BOTH att blocks.
  unsigned mb = 0;
  if (wave < 2) {
    const float* mp = mask + (size_t)b0 * (NAG * NAG) + (wave * 16 + lr) * 32 + lq * 4;
    const float4 m40 = *(const float4*)(mp);
    const float4 m41 = *(const float4*)(mp + 16);
    const float mm[8] = {m40.x, m40.y, m40.z, m40.w, m41.x, m41.y, m41.z, m41.w};
#pragma unroll
    for (int i = 0; i < 8; ++i)
      if (mm[i] != 0.f) mb |= 1u << i;
  }

  // stage x (fp32 -> bf16), swizzled rows
  {
    const float4* xsrc = (const float4*)(x + (size_t)b0 * NAG * DIN);
#pragma unroll
    for (int it = 0; it < 8; ++it) {
      const int q4 = tid + it * 256;
      const float4 v = xsrc[q4];
      bf16x4 s;
      s[0] = f2bf(v.x); s[1] = f2bf(v.y); s[2] = f2bf(v.z); s[3] = f2bf(v.w);
      *(bf16x4*)(XB + offR<512>(q4 >> 6, (q4 & 63) * 8)) = s;
    }
  }
  sbar();

  // encoder: h1[agent][feat] -> P0   (reads XB = P1+P2)
  linearSw4<8, true, 512>(XB, wf + WS_ENC, enc_b, P0, wave, lr, lq, lane);
  sbar();

  // att1: h1=P0 -> Q=P1, K=P2, V=PV; AT=P0 (h1 dead); attout=P1 (Q dead); h2=P2 (K dead)
  att_block4(P0, P1, P2, PV, P0, P1, P2,
             wf + WS_H + 0 * 16384, wf + WS_H + 1 * 16384,
             wf + WS_H + 2 * 16384, wf + WS_H + 3 * 16384,
             b1v, b1k, b1q, b1o, mb, wave, lr, lq, lane);

  // att2: h2=P2 -> Q=P0, K=P1, V=PV; AT=P2; attout=P0; h3=P1
  att_block4(P2, P0, P1, PV, P2, P0, P1,
             wf + WS_H + 4 * 16384, wf + WS_H + 5 * 16384,
             wf + WS_H + 6 * 16384, wf + WS_H + 7 * 16384,
             b2v, b2k, b2q, b2o, mb, wave, lr, lq, lane);

  // head on ALL 4 waves: wave = (action-tile, agent-tile) -> 4 MFMA each
  {
    const int at = wave >> 1, agt = wave & 1;
    f32x4 ha = (f32x4){0.f, 0.f, 0.f, 0.f};
    const bf16x8* wp = (const bf16x8*)(wf + WS_QW);
#pragma unroll
    for (int ks = 0; ks < 4; ++ks) {
      const bf16x8 hf = *(const bf16x8*)(P1 + offR<256>(agt * 16 + lr, ks * 64 + lq * 16));
      ha = __builtin_amdgcn_mfma_f32_16x16x32_bf16(wp[(ks * 2 + at) * 64 + lane], hf, ha, 0, 0, 0);
    }
    const float4 bv4 = *(const float4*)(qb + at * 16 + lq * 4);
    float* op = out + ((size_t)b0 * NAG + agt * 16 + lr) * ADIM;
    float4 o;
    o.x = ha[0] + bv4.x; o.y = ha[1] + bv4.y;
    o.z = ha[2] + bv4.z; o.w = ha[3] + bv4.w;
    *(float4*)(op + at * 16 + lq * 4) = o;
  }
}

extern "C" void kernel_launch(void* const* d_in, const int* in_sizes, int n_in,
                              void* d_out, int out_size, void* d_ws, size_t ws_size,
                              hipStream_t stream)
{
  const float* x     = (const float*)d_in[0];
  const float* mask  = (const float*)d_in[1];
  const float* enc_w = (const float*)d_in[2];
  const float* enc_b = (const float*)d_in[3];
  const float* a1_vw = (const float*)d_in[4];
  const float* a1_vb = (const float*)d_in[5];
  const float* a1_kw = (const float*)d_in[6];
  const float* a1_kb = (const float*)d_in[7];
  const float* a1_qw = (const float*)d_in[8];
  const float* a1_qb = (const float*)d_in[9];
  const float* a1_ow = (const float*)d_in[10];
  const float* a1_ob = (const float*)d_in[11];
  const float* a2_vw = (const float*)d_in[12];
  const float* a2_vb = (const float*)d_in[13];
  const float* a2_kw = (const float*)d_in[14];
  const float* a2_kb = (const float*)d_in[15];
  const float* a2_qw = (const float*)d_in[16];
  const float* a2_qb = (const float*)d_in[17];
  const float* a2_ow = (const float*)d_in[18];
  const float* a2_ob = (const float*)d_in[19];
  const float* q_w   = (const float*)d_in[20];
  const float* q_b   = (const float*)d_in[21];
  short* ws = (short*)d_ws;

  prep_weights<<<164, 256, 0, stream>>>(
      enc_w, a1_vw, a1_kw, a1_qw, a1_ow, a2_vw, a2_kw, a2_qw, a2_ow, q_w, ws);

  dgn_main<<<4096, 256, 0, stream>>>(
      x, mask, enc_b,
      a1_vb, a1_kb, a1_qb, a1_ob,
      a2_vb, a2_kb, a2_qb, a2_ob,
      q_b, ws, (float*)d_out);
}

// Round 7
// 296.448 us; speedup vs baseline: 1.7978x; 1.0141x over previous
//
#include <hip/hip_runtime.h>
#include <hip/hip_bf16.h>

typedef __attribute__((ext_vector_type(8))) short bf16x8;
typedef __attribute__((ext_vector_type(4))) short bf16x4;
typedef __attribute__((ext_vector_type(4))) float f32x4;

#define DEVI static __device__ __forceinline__

constexpr int NAG = 32, DIN = 256, HDIM = 128, ADIM = 32;

// ws layout (bf16 element offsets). Frag order serves both A- and B-orientation:
//   elem ((ks*NM + mt)*64 + lane)*8 + j  <->  W[ks*32 + (lane>>4)*8 + j][mt*16 + (lane&15)]
constexpr int WS_ENC = 0;                  // 256x128
constexpr int WS_H   = 32768;              // 8 mats x 16384
constexpr int WS_QW  = 32768 + 8 * 16384;  // 128x32

// strides (shorts). Row byte-size must be 16B-multiple for ds_read_b128.
constexpr int SH = 136;   // h/Q/K/attout rows [32][136]
constexpr int SV = 40;    // vT rows [128][40]
constexpr int SA = 40;    // AT rows [32][40]
constexpr int SX = 264;   // x staging [32][264]

// LDS byte offsets: P0/P1/P2 = 8704 each, PV = 10240 -> 36352 B -> 4 blocks/CU
constexpr int L_P0 = 0;
constexpr int L_P1 = 8704;
constexpr int L_P2 = 17408;
constexpr int L_PV = 26112;
constexpr int L_TOT = 36352;

// manual RNE f32->bf16 (proven in r0; do NOT replace with v_cvt_pk asm -- r5 NaN'd)
DEVI short f2bf(float f) {
  union { float f; unsigned u; } a; a.f = f;
  return (short)((a.u + 0x7fffu + ((a.u >> 16) & 1u)) >> 16);
}

// ---------------- weight prep: coalesced float4 reads, scattered 2B writes ----
__global__ void prep_weights(const float* __restrict__ enc_w,
                             const float* __restrict__ m0, const float* __restrict__ m1,
                             const float* __restrict__ m2, const float* __restrict__ m3,
                             const float* __restrict__ m4, const float* __restrict__ m5,
                             const float* __restrict__ m6, const float* __restrict__ m7,
                             const float* __restrict__ qw,
                             short* __restrict__ ws)
{
  const int blk = blockIdx.x, tid = threadIdx.x;
  const float* src; int base, NM, nsh, f4;
  if (blk < 32) { src = enc_w; base = WS_ENC; NM = 8; nsh = 7; f4 = blk * 256 + tid; }
  else if (blk < 160) {
    const int m = (blk - 32) >> 4;
    if      (m == 0) src = m0; else if (m == 1) src = m1;
    else if (m == 2) src = m2; else if (m == 3) src = m3;
    else if (m == 4) src = m4; else if (m == 5) src = m5;
    else if (m == 6) src = m6; else             src = m7;
    base = WS_H + (m << 14); NM = 8; nsh = 7; f4 = ((blk - 32) & 15) * 256 + tid;
  } else { src = qw; base = WS_QW; NM = 2; nsh = 5; f4 = (blk - 160) * 256 + tid; }
  const int s = f4 * 4;
  const int row = s >> nsh, col0 = s & ((1 << nsh) - 1);
  const float4 v = *(const float4*)(src + s);
  const int j = row & 7, ks = row >> 5, lhi = ((row >> 3) & 3) * 16;
  const float vv[4] = {v.x, v.y, v.z, v.w};
#pragma unroll
  for (int c = 0; c < 4; ++c) {
    const int col = col0 + c;
    const int mt = col >> 4, lane = lhi + (col & 15);
    ws[base + (((ks * NM + mt) * 64 + lane) << 3) + j] = f2bf(vv[c]);
  }
}

// ---------------- swapped linear on 4 waves: dst[agent][feat], wave = feat group -
// wave mg: m-tiles (features) mg*2+{0,1}; n-tiles (agents) {0,1}
template<int KSTEPS, bool RELU>
DEVI void linearSw4(const short* __restrict__ src, int sstride,
                    const short* __restrict__ wfrag, const float* __restrict__ bias,
                    short* __restrict__ dst,
                    int mg, int lr, int lq, int lane)
{
  f32x4 acc[2][2];
#pragma unroll
  for (int a = 0; a < 2; ++a)
#pragma unroll
    for (int b = 0; b < 2; ++b) acc[a][b] = (f32x4){0.f, 0.f, 0.f, 0.f};

  const bf16x8* wp = (const bf16x8*)wfrag;
#pragma unroll
  for (int ks = 0; ks < KSTEPS; ++ks) {
    bf16x8 hb[2];
#pragma unroll
    for (int b = 0; b < 2; ++b)
      hb[b] = *(const bf16x8*)(src + (b * 16 + lr) * sstride + ks * 32 + lq * 8);
#pragma unroll
    for (int a = 0; a < 2; ++a) {
      const bf16x8 wa = wp[(ks * 8 + mg * 2 + a) * 64 + lane];
#pragma unroll
      for (int b = 0; b < 2; ++b)
        acc[a][b] = __builtin_amdgcn_mfma_f32_16x16x32_bf16(wa, hb[b], acc[a][b], 0, 0, 0);
    }
  }
#pragma unroll
  for (int a = 0; a < 2; ++a) {
    const float4 bv = *(const float4*)(bias + (mg * 2 + a) * 16 + lq * 4);
    const float bb[4] = {bv.x, bv.y, bv.z, bv.w};
#pragma unroll
    for (int b = 0; b < 2; ++b) {
      bf16x4 s;
#pragma unroll
      for (int r = 0; r < 4; ++r) {
        float v = acc[a][b][r] + bb[r];
        if (RELU) v = fmaxf(v, 0.f);
        s[r] = f2bf(v);
      }
      *(bf16x4*)(dst + (b * 16 + lr) * SH + (mg * 2 + a) * 16 + lq * 4) = s;
    }
  }
}

// ---------------- fused QKV: one h-read pass feeds q,k (swapped) and v (normal) -
DEVI void qkv_pass4(const short* __restrict__ h,
                    const short* __restrict__ wq, const short* __restrict__ wk,
                    const short* __restrict__ wv,
                    const float* __restrict__ bq, const float* __restrict__ bk,
                    const float* __restrict__ bv,
                    short* __restrict__ Q, short* __restrict__ K, short* __restrict__ V,
                    int mg, int lr, int lq, int lane)
{
  f32x4 qa[2][2], ka[2][2], va[2][2];
#pragma unroll
  for (int a = 0; a < 2; ++a)
#pragma unroll
    for (int b = 0; b < 2; ++b) {
      qa[a][b] = (f32x4){0.f, 0.f, 0.f, 0.f};
      ka[a][b] = (f32x4){0.f, 0.f, 0.f, 0.f};
      va[a][b] = (f32x4){0.f, 0.f, 0.f, 0.f};
    }
  const bf16x8* wpq = (const bf16x8*)wq;
  const bf16x8* wpk = (const bf16x8*)wk;
  const bf16x8* wpv = (const bf16x8*)wv;
#pragma unroll
  for (int ks = 0; ks < 4; ++ks) {
    bf16x8 hf[2];
#pragma unroll
    for (int b = 0; b < 2; ++b)
      hf[b] = *(const bf16x8*)(h + (b * 16 + lr) * SH + ks * 32 + lq * 8);
#pragma unroll
    for (int a = 0; a < 2; ++a) {
      const bf16x8 wqf = wpq[(ks * 8 + mg * 2 + a) * 64 + lane];
      const bf16x8 wkf = wpk[(ks * 8 + mg * 2 + a) * 64 + lane];
      const bf16x8 wvf = wpv[(ks * 8 + mg * 2 + a) * 64 + lane];
#pragma unroll
      for (int b = 0; b < 2; ++b) {
        qa[a][b] = __builtin_amdgcn_mfma_f32_16x16x32_bf16(wqf, hf[b], qa[a][b], 0, 0, 0);
        ka[a][b] = __builtin_amdgcn_mfma_f32_16x16x32_bf16(wkf, hf[b], ka[a][b], 0, 0, 0);
        va[b][a] = __builtin_amdgcn_mfma_f32_16x16x32_bf16(hf[b], wvf, va[b][a], 0, 0, 0);
      }
    }
  }
  // q, k epilogues: lane holds 4 consecutive features for fixed agent
#pragma unroll
  for (int a = 0; a < 2; ++a) {
    const float4 bq4 = *(const float4*)(bq + (mg * 2 + a) * 16 + lq * 4);
    const float4 bk4 = *(const float4*)(bk + (mg * 2 + a) * 16 + lq * 4);
    const float qb4[4] = {bq4.x, bq4.y, bq4.z, bq4.w};
    const float kb4[4] = {bk4.x, bk4.y, bk4.z, bk4.w};
#pragma unroll
    for (int b = 0; b < 2; ++b) {
      bf16x4 sq, sk;
#pragma unroll
      for (int r = 0; r < 4; ++r) {
        sq[r] = f2bf(fmaxf(qa[a][b][r] + qb4[r], 0.f));
        sk[r] = f2bf(fmaxf(ka[a][b][r] + kb4[r], 0.f));
      }
      const int off = (b * 16 + lr) * SH + (mg * 2 + a) * 16 + lq * 4;
      *(bf16x4*)(Q + off) = sq;
      *(bf16x4*)(K + off) = sk;
    }
  }
  // v epilogue: normal orientation -> vT[feat][agent], 4 consecutive agents/lane
#pragma unroll
  for (int a = 0; a < 2; ++a) {
    const float bvv = bv[(mg * 2 + a) * 16 + lr];
#pragma unroll
    for (int b = 0; b < 2; ++b) {
      bf16x4 sv;
#pragma unroll
      for (int r = 0; r < 4; ++r)
        sv[r] = f2bf(fmaxf(va[b][a][r] + bvv, 0.f));
      *(bf16x4*)(V + ((mg * 2 + a) * 16 + lr) * SV + b * 16 + lq * 4) = sv;
    }
  }
}

// ---------------- scores + softmax on waves 0,1 (qt = wave), in-register -------
// mask bits preloaded once per kernel into 1 VGPR (bit kt*4+r), reused by both atts
DEVI void scores_pass4(const short* __restrict__ Q, const short* __restrict__ K,
                       short* __restrict__ AT, unsigned mb,
                       int qt, int lr, int lq)
{
  f32x4 sc[2];
  sc[0] = (f32x4){0.f, 0.f, 0.f, 0.f};
  sc[1] = (f32x4){0.f, 0.f, 0.f, 0.f};
#pragma unroll
  for (int ks = 0; ks < 4; ++ks) {
    const bf16x8 qf = *(const bf16x8*)(Q + (qt * 16 + lr) * SH + ks * 32 + lq * 8);
#pragma unroll
    for (int kt = 0; kt < 2; ++kt) {
      const bf16x8 kf = *(const bf16x8*)(K + (kt * 16 + lr) * SH + ks * 32 + lq * 8);
      sc[kt] = __builtin_amdgcn_mfma_f32_16x16x32_bf16(kf, qf, sc[kt], 0, 0, 0);
    }
  }
  // lane: q = qt*16+lr (fixed), k = kt*16 + lq*4 + r  (8 logits)
  float l[2][4];
  float M = -3.0e38f;
#pragma unroll
  for (int kt = 0; kt < 2; ++kt)
#pragma unroll
    for (int r = 0; r < 4; ++r) {
      // mask is exactly 0.0/1.0 -> select == scores*mask - 9e15*(1-mask)
      const float v = ((mb >> (kt * 4 + r)) & 1u) ? sc[kt][r] : -9.0e15f;
      l[kt][r] = v;
      M = fmaxf(M, v);
    }
  M = fmaxf(M, __shfl_xor(M, 16));
  M = fmaxf(M, __shfl_xor(M, 32));
  float e[2][4], T = 0.f;
#pragma unroll
  for (int kt = 0; kt < 2; ++kt)
#pragma unroll
    for (int r = 0; r < 4; ++r) { e[kt][r] = __expf(l[kt][r] - M); T += e[kt][r]; }
  T += __shfl_xor(T, 16);
  T += __shfl_xor(T, 32);
  const float rT = __frcp_rn(T);
#pragma unroll
  for (int kt = 0; kt < 2; ++kt) {
    bf16x4 s;
#pragma unroll
    for (int r = 0; r < 4; ++r) s[r] = f2bf(e[kt][r] * rT);
    *(bf16x4*)(AT + (qt * 16 + lr) * SA + kt * 16 + lq * 4) = s;
  }
}

// ---------------- PV: attout[q][feat] = att @ v  (A=vT, B=AT) -------------------
DEVI void pv_pass4(const short* __restrict__ V, const short* __restrict__ AT,
                   short* __restrict__ AO, int wave, int lr, int lq)
{
  bf16x8 atf[2];
#pragma unroll
  for (int qt = 0; qt < 2; ++qt)
    atf[qt] = *(const bf16x8*)(AT + (qt * 16 + lr) * SA + lq * 8);
#pragma unroll
  for (int fi = 0; fi < 2; ++fi) {
    const int f2 = wave * 2 + fi;
    const bf16x8 vf = *(const bf16x8*)(V + (f2 * 16 + lr) * SV + lq * 8);
#pragma unroll
    for (int qt = 0; qt < 2; ++qt) {
      const f32x4 p = __builtin_amdgcn_mfma_f32_16x16x32_bf16(
          vf, atf[qt], (f32x4){0.f, 0.f, 0.f, 0.f}, 0, 0, 0);
      bf16x4 s;
#pragma unroll
      for (int r = 0; r < 4; ++r) s[r] = f2bf(p[r]);
      *(bf16x4*)(AO + (qt * 16 + lr) * SH + f2 * 16 + lq * 4) = s;
    }
  }
}

DEVI void att_block4(const short* Rh, short* RQ, short* RK, short* RV,
                     short* RAT, short* RAO, short* Rout,
                     const short* wv, const short* wk, const short* wq, const short* wo,
                     const float* bv, const float* bk, const float* bq, const float* bo,
                     unsigned mb, int wave, int lr, int lq, int lane)
{
  qkv_pass4(Rh, wq, wk, wv, bq, bk, bv, RQ, RK, RV, wave, lr, lq, lane);
  __syncthreads();
  if (wave < 2) scores_pass4(RQ, RK, RAT, mb, wave, lr, lq);
  __syncthreads();
  pv_pass4(RV, RAT, RAO, wave, lr, lq);
  __syncthreads();
  linearSw4<4, true>(RAO, SH, wo, bo, Rout, wave, lr, lq, lane);
  __syncthreads();
}

// ---------------- fused forward: one block (256 thr) = 1 batch element ---------
__global__ __launch_bounds__(256, 4)
void dgn_main(const float* __restrict__ x, const float* __restrict__ mask,
              const float* __restrict__ enc_b,
              const float* __restrict__ b1v, const float* __restrict__ b1k,
              const float* __restrict__ b1q, const float* __restrict__ b1o,
              const float* __restrict__ b2v, const float* __restrict__ b2k,
              const float* __restrict__ b2q, const float* __restrict__ b2o,
              const float* __restrict__ qb,
              const short* __restrict__ wf,
              float* __restrict__ out)
{
  __shared__ __align__(16) char smem[L_TOT];
  short* P0 = (short*)(smem + L_P0);
  short* P1 = (short*)(smem + L_P1);
  short* P2 = (short*)(smem + L_P2);
  short* PV = (short*)(smem + L_PV);
  short* XB = (short*)(smem + L_P1);   // x staging [32][264] = 16896 B over P1+P2

  const int tid = threadIdx.x;
  const int wave = tid >> 6, lane = tid & 63;
  const int lr = lane & 15, lq = lane >> 4;
  const int b0 = blockIdx.x;

  // mask bit-pack (waves 0,1 only; this wave's q-tile = wave):
  // bit kt*4+r <-> mask[b0][wave*16+lr][kt*16+lq*4+r]. Reused by BOTH att blocks.
  unsigned mb = 0;
  if (wave < 2) {
    const float* mp = mask + (size_t)b0 * (NAG * NAG) + (wave * 16 + lr) * 32 + lq * 4;
    const float4 m40 = *(const float4*)(mp);
    const float4 m41 = *(const float4*)(mp + 16);
    const float mm[8] = {m40.x, m40.y, m40.z, m40.w, m41.x, m41.y, m41.z, m41.w};
#pragma unroll
    for (int i = 0; i < 8; ++i)
      if (mm[i] != 0.f) mb |= 1u << i;
  }

  // stage x (fp32 -> bf16)
  {
    const float4* xsrc = (const float4*)(x + (size_t)b0 * NAG * DIN);
#pragma unroll
    for (int it = 0; it < 8; ++it) {
      const int q4 = tid + it * 256;
      const float4 v = xsrc[q4];
      bf16x4 s;
      s[0] = f2bf(v.x); s[1] = f2bf(v.y); s[2] = f2bf(v.z); s[3] = f2bf(v.w);
      *(bf16x4*)(XB + (q4 >> 6) * SX + (q4 & 63) * 4) = s;
    }
  }
  __syncthreads();

  // encoder: h1[agent][feat] -> P0   (reads XB = P1+P2)
  linearSw4<8, true>(XB, SX, wf + WS_ENC, enc_b, P0, wave, lr, lq, lane);
  __syncthreads();

  // att1: h1=P0 -> Q=P1, K=P2, V=PV; AT=P0 (h1 dead); attout=P1 (Q dead); h2=P2 (K dead)
  att_block4(P0, P1, P2, PV, P0, P1, P2,
             wf + WS_H + 0 * 16384, wf + WS_H + 1 * 16384,
             wf + WS_H + 2 * 16384, wf + WS_H + 3 * 16384,
             b1v, b1k, b1q, b1o, mb, wave, lr, lq, lane);

  // att2: h2=P2 -> Q=P0, K=P1, V=PV; AT=P2; attout=P0; h3=P1
  att_block4(P2, P0, P1, PV, P2, P0, P1,
             wf + WS_H + 4 * 16384, wf + WS_H + 5 * 16384,
             wf + WS_H + 6 * 16384, wf + WS_H + 7 * 16384,
             b2v, b2k, b2q, b2o, mb, wave, lr, lq, lane);

  // head on ALL 4 waves: wave = (action-tile, agent-tile) -> 4 MFMA each
  {
    const int at = wave >> 1, agt = wave & 1;
    f32x4 ha = (f32x4){0.f, 0.f, 0.f, 0.f};
    const bf16x8* wp = (const bf16x8*)(wf + WS_QW);
#pragma unroll
    for (int ks = 0; ks < 4; ++ks) {
      const bf16x8 hf = *(const bf16x8*)(P1 + (agt * 16 + lr) * SH + ks * 32 + lq * 8);
      ha = __builtin_amdgcn_mfma_f32_16x16x32_bf16(wp[(ks * 2 + at) * 64 + lane], hf, ha, 0, 0, 0);
    }
    const float4 bv4 = *(const float4*)(qb + at * 16 + lq * 4);
    float* op = out + ((size_t)b0 * NAG + agt * 16 + lr) * ADIM;
    float4 o;
    o.x = ha[0] + bv4.x; o.y = ha[1] + bv4.y;
    o.z = ha[2] + bv4.z; o.w = ha[3] + bv4.w;
    *(float4*)(op + at * 16 + lq * 4) = o;
  }
}

extern "C" void kernel_launch(void* const* d_in, const int* in_sizes, int n_in,
                              void* d_out, int out_size, void* d_ws, size_t ws_size,
                              hipStream_t stream)
{
  const float* x     = (const float*)d_in[0];
  const float* mask  = (const float*)d_in[1];
  const float* enc_w = (const float*)d_in[2];
  const float* enc_b = (const float*)d_in[3];
  const float* a1_vw = (const float*)d_in[4];
  const float* a1_vb = (const float*)d_in[5];
  const float* a1_kw = (const float*)d_in[6];
  const float* a1_kb = (const float*)d_in[7];
  const float* a1_qw = (const float*)d_in[8];
  const float* a1_qb = (const float*)d_in[9];
  const float* a1_ow = (const float*)d_in[10];
  const float* a1_ob = (const float*)d_in[11];
  const float* a2_vw = (const float*)d_in[12];
  const float* a2_vb = (const float*)d_in[13];
  const float* a2_kw = (const float*)d_in[14];
  const float* a2_kb = (const float*)d_in[15];
  const float* a2_qw = (const float*)d_in[16];
  const float* a2_qb = (const float*)d_in[17];
  const float* a2_ow = (const float*)d_in[18];
  const float* a2_ob = (const float*)d_in[19];
  const float* q_w   = (const float*)d_in[20];
  const float* q_b   = (const float*)d_in[21];
  short* ws = (short*)d_ws;

  prep_weights<<<164, 256, 0, stream>>>(
      enc_w, a1_vw, a1_kw, a1_qw, a1_ow, a2_vw, a2_kw, a2_qw, a2_ow, q_w, ws);

  dgn_main<<<4096, 256, 0, stream>>>(
      x, mask, enc_b,
      a1_vb, a1_kb, a1_qb, a1_ob,
      a2_vb, a2_kb, a2_qb, a2_ob,
      q_b, ws, (float*)d_out);
}